// Round 5
// baseline (228.791 us; speedup 1.0000x reference)
//
#include <hip/hip_runtime.h>
#include <type_traits>

// DrQv2 random-shift augmentation.
// out[b,c,i,j] = x[b,c, clamp(i+dy,0,H-1), clamp(j+dx,0,W-1)],  d = shift-PAD
//
// Key fact: dx is uniform per block (per image). So the shifted row read
// decomposes into ALIGNED float4 loads + a uniform in-register rotation:
//   j0 = 4*j4 + dx ; q = j4 + (dx>>2) ; r = dx & 3
//   out4 = rotate_r( row4[q], row4[q+1] )      (+ per-lane edge clamps)
// -> copy-kernel access shape: aligned dwordx4 in, aligned dwordx4 out,
//    no LDS, no barriers, all 14 loads per thread hoisted before stores.

#define PAD 4

constexpr int CC     = 9;
constexpr int H      = 84;
constexpr int W      = 84;
constexpr int PLANE  = H * W;        // 7056 floats
constexpr int PLANE4 = PLANE / 4;    // 1764 float4
constexpr int W4     = W / 4;        // 21 float4 per row
constexpr int NBLK   = 512 * CC;     // one block per (b,c) plane

__global__ __launch_bounds__(256, 4)
void drq_aug_kernel(const float* __restrict__ x,
                    const int*   __restrict__ shift,
                    float*       __restrict__ out)
{
    const int blk = blockIdx.x;            // blk = b*C + c
    const int b   = blk / CC;
    const int dx  = shift[2 * b]     - PAD;   // block-uniform -> SGPR
    const int dy  = shift[2 * b + 1] - PAD;
    const int qoff = dx >> 2;                 // floor(dx/4), in {-1,0,1}
    const int rot  = dx & 3;

    const float4* __restrict__ src4 = (const float4*)(x   + (size_t)blk * PLANE);
    float4*       __restrict__ dst4 = (float4*)      (out + (size_t)blk * PLANE);

    const int tid = threadIdx.x;

    float4 A[7], B[7];
    int    c0_[7];
    bool   act[7];

    // ---- phase 1: issue all aligned loads (deep VMEM pipeline) ----
    #pragma unroll
    for (int rr = 0; rr < 7; ++rr) {
        int p  = rr * 256 + tid;
        act[rr] = (p < PLANE4);
        int pc = act[rr] ? p : PLANE4 - 1;
        int i  = pc / W4;
        int j4 = pc - i * W4;
        int si = i + dy;  si = si < 0 ? 0 : (si > H - 1 ? H - 1 : si);
        int q  = j4 + qoff;                      // in [-1, 21]
        int q0 = q < 0 ? 0 : (q > W4 - 1 ? W4 - 1 : q);
        int q1 = q + 1;
        q1 = q1 < 0 ? 0 : (q1 > W4 - 1 ? W4 - 1 : q1);
        const float4* __restrict__ row4 = src4 + si * W4;
        A[rr] = row4[q0];
        B[rr] = row4[q1];
        c0_[rr] = (j4 << 2) + dx;                // column of element 0
    }

    // ---- phase 2: uniform rotate (compile-time specialized), edge fix, store
    auto body = [&](auto rotc) {
        constexpr int R = decltype(rotc)::value;
        #pragma unroll
        for (int rr = 0; rr < 7; ++rr) {
            float4 a = A[rr], bb = B[rr];
            float4 v;
            if constexpr (R == 0)      v = a;
            else if constexpr (R == 1) v = make_float4(a.y, a.z, a.w, bb.x);
            else if constexpr (R == 2) v = make_float4(a.z, a.w, bb.x, bb.y);
            else                       v = make_float4(a.w, bb.x, bb.y, bb.z);
            int c0 = c0_[rr];
            if (dx < 0) {                         // uniform guard
                // c<0 => j4==0, q0==0, so row[0] == a.x
                v.x = (c0     < 0) ? a.x : v.x;
                v.y = (c0 + 1 < 0) ? a.x : v.y;
                v.z = (c0 + 2 < 0) ? a.x : v.z;
                v.w = (c0 + 3 < 0) ? a.x : v.w;
            } else if (dx > 0) {
                // c>83 => j4==20, q1==20, so row[83] == bb.w
                v.x = (c0     > W - 1) ? bb.w : v.x;
                v.y = (c0 + 1 > W - 1) ? bb.w : v.y;
                v.z = (c0 + 2 > W - 1) ? bb.w : v.z;
                v.w = (c0 + 3 > W - 1) ? bb.w : v.w;
            }
            if (act[rr]) dst4[rr * 256 + tid] = v;
        }
    };

    switch (rot) {
        case 0:  body(std::integral_constant<int, 0>{}); break;
        case 1:  body(std::integral_constant<int, 1>{}); break;
        case 2:  body(std::integral_constant<int, 2>{}); break;
        default: body(std::integral_constant<int, 3>{}); break;
    }
}

extern "C" void kernel_launch(void* const* d_in, const int* in_sizes, int n_in,
                              void* d_out, int out_size, void* d_ws, size_t ws_size,
                              hipStream_t stream)
{
    const float* x     = (const float*)d_in[0];
    const int*   shift = (const int*)d_in[1];
    float*       out   = (float*)d_out;

    drq_aug_kernel<<<NBLK, 256, 0, stream>>>(x, shift, out);
}

// Round 8
// 215.888 us; speedup vs baseline: 1.0598x; 1.0598x over previous
//
#include <hip/hip_runtime.h>
#include <type_traits>

// DrQv2 random-shift augmentation.
// out[b,c,i,j] = x[b,c, clamp(i+dy,0,H-1), clamp(j+dx,0,W-1)],  d = shift-PAD
//
// ONE output float4 per thread (no per-thread loop -> compiler cannot
// serialize the load pipeline; concurrency is pure TLP, fill-kernel style).
// dx uniform per block -> aligned float4 loads + uniform in-register rotate:
//   q = j4 + (dx>>2); r = dx&3; out4 = rotate_r(row4[q], row4[q+1]) + edge fix.

#define PAD 4

constexpr int CC     = 9;
constexpr int H      = 84;
constexpr int W      = 84;
constexpr int PLANE  = H * W;        // 7056 floats
constexpr int PLANE4 = PLANE / 4;    // 1764 float4
constexpr int W4     = W / 4;        // 21 float4 per row
constexpr int SUBS   = 7;            // ceil(1764 / 256)
constexpr int NBLK   = 512 * CC * SUBS;   // 32256 blocks

typedef float vf4 __attribute__((ext_vector_type(4)));   // native vec for NT store

__global__ __launch_bounds__(256)
void drq_aug_kernel(const float* __restrict__ x,
                    const int*   __restrict__ shift,
                    float*       __restrict__ out)
{
    const int bid   = blockIdx.x;
    const int plane = bid / SUBS;          // (b*C + c)
    const int sub   = bid - plane * SUBS;

    const int p = sub * 256 + (int)threadIdx.x;   // output float4 index in plane
    if (p >= PLANE4) return;

    const int b  = plane / CC;
    const int dx = shift[2 * b]     - PAD;   // block-uniform -> SGPR
    const int dy = shift[2 * b + 1] - PAD;
    const int qoff = dx >> 2;                // in {-1,0,1}
    const int rot  = dx & 3;

    const float4* __restrict__ src4 = (const float4*)(x   + (size_t)plane * PLANE);
    float*        __restrict__ dstf = out + (size_t)plane * PLANE;

    const int i  = p / W4;
    const int j4 = p - i * W4;
    int si = i + dy;  si = si < 0 ? 0 : (si > H - 1 ? H - 1 : si);

    int q  = j4 + qoff;                      // in [-1, 21]
    int q0 = q < 0 ? 0 : (q > W4 - 1 ? W4 - 1 : q);
    int q1 = q + 1;
    q1 = q1 < 0 ? 0 : (q1 > W4 - 1 ? W4 - 1 : q1);

    const float4* __restrict__ row4 = src4 + si * W4;
    const float4 a  = row4[q0];              // two independent aligned loads,
    const float4 bb = row4[q1];              // one wait, done.

    const int c0 = (j4 << 2) + dx;           // column of element 0

    auto body = [&](auto rotc) {
        constexpr int R = decltype(rotc)::value;
        float4 v;
        if constexpr (R == 0)      v = a;
        else if constexpr (R == 1) v = make_float4(a.y, a.z, a.w, bb.x);
        else if constexpr (R == 2) v = make_float4(a.z, a.w, bb.x, bb.y);
        else                       v = make_float4(a.w, bb.x, bb.y, bb.z);
        if (dx < 0) {                        // uniform guard; c<0 => row[0]==a.x
            v.x = (c0     < 0) ? a.x : v.x;
            v.y = (c0 + 1 < 0) ? a.x : v.y;
            v.z = (c0 + 2 < 0) ? a.x : v.z;
            v.w = (c0 + 3 < 0) ? a.x : v.w;
        } else if (dx > 0) {                 // c>83 => row[83]==bb.w
            v.x = (c0     > W - 1) ? bb.w : v.x;
            v.y = (c0 + 1 > W - 1) ? bb.w : v.y;
            v.z = (c0 + 2 > W - 1) ? bb.w : v.z;
            v.w = (c0 + 3 > W - 1) ? bb.w : v.w;
        }
        vf4 nv = { v.x, v.y, v.z, v.w };
        __builtin_nontemporal_store(nv, (vf4*)(dstf + 4 * p));
    };

    switch (rot) {
        case 0:  body(std::integral_constant<int, 0>{}); break;
        case 1:  body(std::integral_constant<int, 1>{}); break;
        case 2:  body(std::integral_constant<int, 2>{}); break;
        default: body(std::integral_constant<int, 3>{}); break;
    }
}

extern "C" void kernel_launch(void* const* d_in, const int* in_sizes, int n_in,
                              void* d_out, int out_size, void* d_ws, size_t ws_size,
                              hipStream_t stream)
{
    const float* x     = (const float*)d_in[0];
    const int*   shift = (const int*)d_in[1];
    float*       out   = (float*)d_out;

    drq_aug_kernel<<<NBLK, 256, 0, stream>>>(x, shift, out);
}